// Round 2
// baseline (462.253 us; speedup 1.0000x reference)
//
#include <hip/hip_runtime.h>
#include <math.h>

// Problem constants (from setup_inputs): B=16384, M=64, D=16, NR=24, N_HOP=2
#define NHOP 2
#define BSZ 16384
#define MSZ 64
#define NREL 24
#define KGE_W 0.01
#define L2_W 1e-7

#define WAVES_PER_BLOCK 4
#define NB_PER_WAVE 2
#define GRID_BLKS (BSZ / (WAVES_PER_BLOCK * NB_PER_WAVE))  // 2048

typedef float v2f __attribute__((ext_vector_type(2)));

__device__ __forceinline__ float wave_sum(float v) {
#pragma unroll
    for (int off = 32; off > 0; off >>= 1) v += __shfl_xor(v, off, 64);
    return v;
}

__device__ __forceinline__ float wave_max(float v) {
#pragma unroll
    for (int off = 32; off > 0; off >>= 1) v = fmaxf(v, __shfl_xor(v, off, 64));
    return v;
}

// Precompute per-relation sum of squares: (r*r).sum() for each of 24 relations.
__global__ void relsumsq_kernel(const float* __restrict__ rel, float* __restrict__ out) {
    int r = blockIdx.x;
    int lane = threadIdx.x;  // 64 lanes, each loads 4 floats (256 total)
    const float4* rp = reinterpret_cast<const float4*>(rel + (size_t)r * 256);
    float4 v = rp[lane];
    float s = v.x * v.x + v.y * v.y + v.z * v.z + v.w * v.w;
    s = wave_sum(s);
    if (lane == 0) out[r] = s;
}

__global__ __launch_bounds__(256) void ripple_kernel(
    const float* __restrict__ ent,      // [NE,16]
    const float* __restrict__ rel,      // [24,256]
    const int* __restrict__ items,      // [B]
    const int* __restrict__ labels,     // [B]
    const int* __restrict__ mh,         // [2,B,64]
    const int* __restrict__ mr,
    const int* __restrict__ mt,
    const float* __restrict__ relsq,    // [24]
    float* __restrict__ scores,         // [B]
    double* __restrict__ partials)      // [GRID_BLKS][3]: base, kge, l2
{
    const int lane = threadIdx.x & 63;
    const int wave = threadIdx.x >> 6;

    float base_loc = 0.f;  // only lane 0 accumulates
    float kge_loc = 0.f;
    float l2_loc = 0.f;

    for (int nb = 0; nb < NB_PER_WAVE; ++nb) {
        const int b = (blockIdx.x * WAVES_PER_BLOCK + wave) * NB_PER_WAVE + nb;

        float item[16], y[16];
        {
            const float4* p4 = reinterpret_cast<const float4*>(ent + (size_t)items[b] * 16);
            float4 a = p4[0], c = p4[1], d4 = p4[2], e = p4[3];
            item[0] = a.x; item[1] = a.y; item[2] = a.z; item[3] = a.w;
            item[4] = c.x; item[5] = c.y; item[6] = c.z; item[7] = c.w;
            item[8] = d4.x; item[9] = d4.y; item[10] = d4.z; item[11] = d4.w;
            item[12] = e.x; item[13] = e.y; item[14] = e.z; item[15] = e.w;
        }
#pragma unroll
        for (int d = 0; d < 16; ++d) y[d] = 0.f;
        const float lab = (float)labels[b];

        for (int hop = 0; hop < NHOP; ++hop) {
            const size_t idx = (size_t)hop * BSZ * MSZ + (size_t)b * MSZ + lane;
            const int ih = mh[idx];
            const int ir = mr[idx];
            const int it = mt[idx];

            // Interleave h,t as float2 pairs so packed fp32 FMA (v_pk_fma_f32)
            // can compute the R*h (score) and R*t (kge) streams together.
            v2f ht[16];
            {
                const float4* hp = reinterpret_cast<const float4*>(ent + (size_t)ih * 16);
                const float4* tp = reinterpret_cast<const float4*>(ent + (size_t)it * 16);
#pragma unroll
                for (int q = 0; q < 4; ++q) {
                    float4 hv = hp[q], tv = tp[q];
                    ht[q * 4 + 0] = (v2f){hv.x, tv.x};
                    ht[q * 4 + 1] = (v2f){hv.y, tv.y};
                    ht[q * 4 + 2] = (v2f){hv.z, tv.z};
                    ht[q * 4 + 3] = (v2f){hv.w, tv.w};
                }
            }

            const float4* rp = reinterpret_cast<const float4*>(rel + (size_t)ir * 256);

            // sc2 = {score, hRt}: score = item.(R h); hRt = h.(R t)
            v2f sc2 = (v2f){0.f, 0.f};
#pragma unroll
            for (int i = 0; i < 16; ++i) {
                const float4 r0 = rp[4 * i + 0];
                const float4 r1 = rp[4 * i + 1];
                const float4 r2 = rp[4 * i + 2];
                const float4 r3 = rp[4 * i + 3];
                v2f a = (v2f){0.f, 0.f};
                a = __builtin_elementwise_fma((v2f){r0.x, r0.x}, ht[0], a);
                a = __builtin_elementwise_fma((v2f){r0.y, r0.y}, ht[1], a);
                a = __builtin_elementwise_fma((v2f){r0.z, r0.z}, ht[2], a);
                a = __builtin_elementwise_fma((v2f){r0.w, r0.w}, ht[3], a);
                a = __builtin_elementwise_fma((v2f){r1.x, r1.x}, ht[4], a);
                a = __builtin_elementwise_fma((v2f){r1.y, r1.y}, ht[5], a);
                a = __builtin_elementwise_fma((v2f){r1.z, r1.z}, ht[6], a);
                a = __builtin_elementwise_fma((v2f){r1.w, r1.w}, ht[7], a);
                a = __builtin_elementwise_fma((v2f){r2.x, r2.x}, ht[8], a);
                a = __builtin_elementwise_fma((v2f){r2.y, r2.y}, ht[9], a);
                a = __builtin_elementwise_fma((v2f){r2.z, r2.z}, ht[10], a);
                a = __builtin_elementwise_fma((v2f){r2.w, r2.w}, ht[11], a);
                a = __builtin_elementwise_fma((v2f){r3.x, r3.x}, ht[12], a);
                a = __builtin_elementwise_fma((v2f){r3.y, r3.y}, ht[13], a);
                a = __builtin_elementwise_fma((v2f){r3.z, r3.z}, ht[14], a);
                a = __builtin_elementwise_fma((v2f){r3.w, r3.w}, ht[15], a);
                // a = {(R h)_i, (R t)_i}; fold into {score, hRt}
                sc2 = __builtin_elementwise_fma(a, (v2f){item[i], ht[i].x}, sc2);
            }

            // softmax over the 64 memories (one per lane)
            const float mx = wave_max(sc2.x);
            const float e = __expf(sc2.x - mx);
            const float s = wave_sum(e);
            const float p = e / s;

            // o_d = sum_m p_m * t[m][d]; broadcast to all lanes via butterfly
#pragma unroll
            for (int d = 0; d < 16; ++d) {
                const float od = wave_sum(p * ht[d].y);
                item[d] += od;
                y[d] += od;
            }

            // kge: sigmoid(h^T R t)
            kge_loc += 1.f / (1.f + __expf(-sc2.y));

            // l2: h^2 + t^2 + r^2 (r^2 precomputed per relation)
            v2f l2a = (v2f){0.f, 0.f};
#pragma unroll
            for (int d = 0; d < 16; ++d) l2a = __builtin_elementwise_fma(ht[d], ht[d], l2a);
            l2_loc += relsq[ir] + l2a.x + l2a.y;
        }

        // logits = item_final . y ; all lanes hold identical values
        float logit = 0.f;
#pragma unroll
        for (int d = 0; d < 16; ++d) logit = fmaf(item[d], y[d], logit);

        if (lane == 0) {
            scores[b] = 1.f / (1.f + __expf(-logit));
            // (1-lab)*z + softplus(-z), stable
            base_loc += (1.f - lab) * logit + fmaxf(-logit, 0.f) + log1pf(expf(-fabsf(logit)));
        }
    }

    kge_loc = wave_sum(kge_loc);
    l2_loc = wave_sum(l2_loc);

    __shared__ double sred[WAVES_PER_BLOCK][3];
    if (lane == 0) {
        sred[wave][0] = (double)base_loc;
        sred[wave][1] = (double)kge_loc;
        sred[wave][2] = (double)l2_loc;
    }
    __syncthreads();
    if (threadIdx.x < 3) {
        double acc = 0.0;
        for (int w = 0; w < WAVES_PER_BLOCK; ++w) acc += sred[w][threadIdx.x];
        partials[(size_t)blockIdx.x * 3 + threadIdx.x] = acc;
    }
}

__global__ void finalize_kernel(const double* __restrict__ partials, float* __restrict__ out_loss) {
    const int lane = threadIdx.x;  // 64 threads
    double b0 = 0.0, b1 = 0.0, b2 = 0.0;
    for (int i = lane; i < GRID_BLKS; i += 64) {
        b0 += partials[(size_t)i * 3 + 0];
        b1 += partials[(size_t)i * 3 + 1];
        b2 += partials[(size_t)i * 3 + 2];
    }
#pragma unroll
    for (int off = 32; off > 0; off >>= 1) {
        b0 += __shfl_xor(b0, off, 64);
        b1 += __shfl_xor(b1, off, 64);
        b2 += __shfl_xor(b2, off, 64);
    }
    if (lane == 0) {
        const double base = b0 / (double)BSZ;
        const double kge = b1 / ((double)BSZ * (double)MSZ);
        const double l2 = b2;
        out_loss[0] = (float)(base - KGE_W * kge + L2_W * l2);
    }
}

extern "C" void kernel_launch(void* const* d_in, const int* in_sizes, int n_in,
                              void* d_out, int out_size, void* d_ws, size_t ws_size,
                              hipStream_t stream) {
    const float* ent    = (const float*)d_in[0];
    const float* rel    = (const float*)d_in[1];
    const int*   items  = (const int*)d_in[2];
    const int*   labels = (const int*)d_in[3];
    const int*   mh     = (const int*)d_in[4];
    const int*   mr     = (const int*)d_in[5];
    const int*   mt     = (const int*)d_in[6];

    float* out = (float*)d_out;              // scores[16384] then loss at [16384]
    float* relsq = (float*)d_ws;             // 24 floats
    double* partials = (double*)((char*)d_ws + 256);  // GRID_BLKS*3 doubles

    relsumsq_kernel<<<NREL, 64, 0, stream>>>(rel, relsq);
    ripple_kernel<<<GRID_BLKS, 256, 0, stream>>>(ent, rel, items, labels, mh, mr, mt,
                                                 relsq, out, partials);
    finalize_kernel<<<1, 64, 0, stream>>>(partials, out + BSZ);
}

// Round 16
// 398.027 us; speedup vs baseline: 1.1614x; 1.1614x over previous
//
#include <hip/hip_runtime.h>
#include <math.h>

// Problem constants (from setup_inputs): B=16384, M=64, D=16, NR=24, N_HOP=2
#define NHOP 2
#define BSZ 16384
#define MSZ 64
#define NREL 24
#define KGE_W 0.01
#define L2_W 1e-7

#define WAVES_PER_BLOCK 4
#define GRID_BLKS (BSZ / WAVES_PER_BLOCK)  // 4096 blocks, one b per wave

typedef float v2f __attribute__((ext_vector_type(2)));

__device__ __forceinline__ float wave_sum(float v) {
#pragma unroll
    for (int off = 32; off > 0; off >>= 1) v += __shfl_xor(v, off, 64);
    return v;
}

__device__ __forceinline__ float wave_max(float v) {
#pragma unroll
    for (int off = 32; off > 0; off >>= 1) v = fmaxf(v, __shfl_xor(v, off, 64));
    return v;
}

// Precompute per-relation sum of squares: (r*r).sum() for each of 24 relations.
__global__ void relsumsq_kernel(const float* __restrict__ rel, float* __restrict__ out) {
    int r = blockIdx.x;
    int lane = threadIdx.x;  // 64 lanes, each loads 4 floats (256 total)
    const float4* rp = reinterpret_cast<const float4*>(rel + (size_t)r * 256);
    float4 v = rp[lane];
    float s = v.x * v.x + v.y * v.y + v.z * v.z + v.w * v.w;
    s = wave_sum(s);
    if (lane == 0) out[r] = s;
}

__global__ __launch_bounds__(256) void ripple_kernel(
    const float* __restrict__ ent,      // [NE,16]
    const float* __restrict__ rel,      // [24,256]
    const int* __restrict__ items,      // [B]
    const int* __restrict__ labels,     // [B]
    const int* __restrict__ mh,         // [2,B,64]
    const int* __restrict__ mr,
    const int* __restrict__ mt,
    const float* __restrict__ relsq,    // [24]
    float* __restrict__ scores,         // [B]
    double* __restrict__ partials)      // [GRID_BLKS][3]: base, kge, l2
{
    const int lane = threadIdx.x & 63;
    const int wave = threadIdx.x >> 6;
    const int b = blockIdx.x * WAVES_PER_BLOCK + wave;

    // ---- all index loads upfront (coalesced, both hops) ----
    const size_t i0 = (size_t)b * MSZ + lane;
    const size_t i1 = (size_t)BSZ * MSZ + i0;
    const int ih0 = mh[i0], ir0 = mr[i0], it0 = mt[i0];
    const int ih1 = mh[i1], ir1 = mr[i1], it1 = mt[i1];

    // ---- all entity gathers upfront: 16 independent float4 loads + item ----
    const float4* h0p = reinterpret_cast<const float4*>(ent + (size_t)ih0 * 16);
    const float4* t0p = reinterpret_cast<const float4*>(ent + (size_t)it0 * 16);
    const float4* h1p = reinterpret_cast<const float4*>(ent + (size_t)ih1 * 16);
    const float4* t1p = reinterpret_cast<const float4*>(ent + (size_t)it1 * 16);
    const float4* ip  = reinterpret_cast<const float4*>(ent + (size_t)items[b] * 16);

    float4 h0q[4], t0q[4], h1q[4], t1q[4], iq[4];
#pragma unroll
    for (int q = 0; q < 4; ++q) h0q[q] = h0p[q];
#pragma unroll
    for (int q = 0; q < 4; ++q) t0q[q] = t0p[q];
#pragma unroll
    for (int q = 0; q < 4; ++q) h1q[q] = h1p[q];
#pragma unroll
    for (int q = 0; q < 4; ++q) t1q[q] = t1p[q];
#pragma unroll
    for (int q = 0; q < 4; ++q) iq[q] = ip[q];

    // interleave h,t as float2 so packed fp32 FMA (v_pk_fma_f32) computes
    // the R*h and R*t streams together
    v2f ht0[16], ht1[16];
#pragma unroll
    for (int q = 0; q < 4; ++q) {
        ht0[q * 4 + 0] = (v2f){h0q[q].x, t0q[q].x};
        ht0[q * 4 + 1] = (v2f){h0q[q].y, t0q[q].y};
        ht0[q * 4 + 2] = (v2f){h0q[q].z, t0q[q].z};
        ht0[q * 4 + 3] = (v2f){h0q[q].w, t0q[q].w};
        ht1[q * 4 + 0] = (v2f){h1q[q].x, t1q[q].x};
        ht1[q * 4 + 1] = (v2f){h1q[q].y, t1q[q].y};
        ht1[q * 4 + 2] = (v2f){h1q[q].z, t1q[q].z};
        ht1[q * 4 + 3] = (v2f){h1q[q].w, t1q[q].w};
    }
    float item[16], y[16];
#pragma unroll
    for (int q = 0; q < 4; ++q) {
        item[q * 4 + 0] = iq[q].x; item[q * 4 + 1] = iq[q].y;
        item[q * 4 + 2] = iq[q].z; item[q * 4 + 3] = iq[q].w;
    }
#pragma unroll
    for (int d = 0; d < 16; ++d) y[d] = 0.f;

    // ---- hop0 matvecs: {score0, hRt0} folded on the fly ----
    const float4* r0p = reinterpret_cast<const float4*>(rel + (size_t)ir0 * 256);
    v2f sc0 = (v2f){0.f, 0.f};
#pragma unroll
    for (int i = 0; i < 16; ++i) {
        const float4 r0 = r0p[4 * i + 0];
        const float4 r1 = r0p[4 * i + 1];
        const float4 r2 = r0p[4 * i + 2];
        const float4 r3 = r0p[4 * i + 3];
        v2f a = (v2f){0.f, 0.f};
        a = __builtin_elementwise_fma((v2f){r0.x, r0.x}, ht0[0], a);
        a = __builtin_elementwise_fma((v2f){r0.y, r0.y}, ht0[1], a);
        a = __builtin_elementwise_fma((v2f){r0.z, r0.z}, ht0[2], a);
        a = __builtin_elementwise_fma((v2f){r0.w, r0.w}, ht0[3], a);
        a = __builtin_elementwise_fma((v2f){r1.x, r1.x}, ht0[4], a);
        a = __builtin_elementwise_fma((v2f){r1.y, r1.y}, ht0[5], a);
        a = __builtin_elementwise_fma((v2f){r1.z, r1.z}, ht0[6], a);
        a = __builtin_elementwise_fma((v2f){r1.w, r1.w}, ht0[7], a);
        a = __builtin_elementwise_fma((v2f){r2.x, r2.x}, ht0[8], a);
        a = __builtin_elementwise_fma((v2f){r2.y, r2.y}, ht0[9], a);
        a = __builtin_elementwise_fma((v2f){r2.z, r2.z}, ht0[10], a);
        a = __builtin_elementwise_fma((v2f){r2.w, r2.w}, ht0[11], a);
        a = __builtin_elementwise_fma((v2f){r3.x, r3.x}, ht0[12], a);
        a = __builtin_elementwise_fma((v2f){r3.y, r3.y}, ht0[13], a);
        a = __builtin_elementwise_fma((v2f){r3.z, r3.z}, ht0[14], a);
        a = __builtin_elementwise_fma((v2f){r3.w, r3.w}, ht0[15], a);
        sc0 = __builtin_elementwise_fma(a, (v2f){item[i], ht0[i].x}, sc0);
    }

    // ---- hop1 matvecs NOW (independent of hop0 softmax): keep Rh1, fold hRt1 ----
    const float4* r1p = reinterpret_cast<const float4*>(rel + (size_t)ir1 * 256);
    float Rh1[16];
    float hRt1 = 0.f;
#pragma unroll
    for (int i = 0; i < 16; ++i) {
        const float4 r0 = r1p[4 * i + 0];
        const float4 r1 = r1p[4 * i + 1];
        const float4 r2 = r1p[4 * i + 2];
        const float4 r3 = r1p[4 * i + 3];
        v2f a = (v2f){0.f, 0.f};
        a = __builtin_elementwise_fma((v2f){r0.x, r0.x}, ht1[0], a);
        a = __builtin_elementwise_fma((v2f){r0.y, r0.y}, ht1[1], a);
        a = __builtin_elementwise_fma((v2f){r0.z, r0.z}, ht1[2], a);
        a = __builtin_elementwise_fma((v2f){r0.w, r0.w}, ht1[3], a);
        a = __builtin_elementwise_fma((v2f){r1.x, r1.x}, ht1[4], a);
        a = __builtin_elementwise_fma((v2f){r1.y, r1.y}, ht1[5], a);
        a = __builtin_elementwise_fma((v2f){r1.z, r1.z}, ht1[6], a);
        a = __builtin_elementwise_fma((v2f){r1.w, r1.w}, ht1[7], a);
        a = __builtin_elementwise_fma((v2f){r2.x, r2.x}, ht1[8], a);
        a = __builtin_elementwise_fma((v2f){r2.y, r2.y}, ht1[9], a);
        a = __builtin_elementwise_fma((v2f){r2.z, r2.z}, ht1[10], a);
        a = __builtin_elementwise_fma((v2f){r2.w, r2.w}, ht1[11], a);
        a = __builtin_elementwise_fma((v2f){r3.x, r3.x}, ht1[12], a);
        a = __builtin_elementwise_fma((v2f){r3.y, r3.y}, ht1[13], a);
        a = __builtin_elementwise_fma((v2f){r3.z, r3.z}, ht1[14], a);
        a = __builtin_elementwise_fma((v2f){r3.w, r3.w}, ht1[15], a);
        Rh1[i] = a.x;
        hRt1 = fmaf(ht1[i].x, a.y, hRt1);
    }

    // ---- hop0 softmax + o-update ----
    {
        const float mx = wave_max(sc0.x);
        const float e = __expf(sc0.x - mx);
        const float s = wave_sum(e);
        const float p = e / s;
#pragma unroll
        for (int d = 0; d < 16; ++d) {
            const float od = wave_sum(p * ht0[d].y);
            item[d] += od;
            y[d] += od;
        }
    }

    // ---- hop1: score is just a 16-FMA dot with the updated item ----
    {
        float score = 0.f;
#pragma unroll
        for (int i = 0; i < 16; ++i) score = fmaf(item[i], Rh1[i], score);
        const float mx = wave_max(score);
        const float e = __expf(score - mx);
        const float s = wave_sum(e);
        const float p = e / s;
#pragma unroll
        for (int d = 0; d < 16; ++d) {
            const float od = wave_sum(p * ht1[d].y);
            item[d] += od;
            y[d] += od;
        }
    }

    // ---- kge + l2 ----
    float kge_loc = 1.f / (1.f + __expf(-sc0.y)) + 1.f / (1.f + __expf(-hRt1));
    v2f l2a = (v2f){0.f, 0.f};
#pragma unroll
    for (int d = 0; d < 16; ++d) {
        l2a = __builtin_elementwise_fma(ht0[d], ht0[d], l2a);
        l2a = __builtin_elementwise_fma(ht1[d], ht1[d], l2a);
    }
    float l2_loc = relsq[ir0] + relsq[ir1] + l2a.x + l2a.y;

    // ---- logits / scores / base loss ----
    float logit = 0.f;
#pragma unroll
    for (int d = 0; d < 16; ++d) logit = fmaf(item[d], y[d], logit);

    float base_loc = 0.f;
    if (lane == 0) {
        scores[b] = 1.f / (1.f + __expf(-logit));
        const float lab = (float)labels[b];
        base_loc = (1.f - lab) * logit + fmaxf(-logit, 0.f) + log1pf(expf(-fabsf(logit)));
    }

    kge_loc = wave_sum(kge_loc);
    l2_loc = wave_sum(l2_loc);

    __shared__ double sred[WAVES_PER_BLOCK][3];
    if (lane == 0) {
        sred[wave][0] = (double)base_loc;
        sred[wave][1] = (double)kge_loc;
        sred[wave][2] = (double)l2_loc;
    }
    __syncthreads();
    if (threadIdx.x < 3) {
        double acc = 0.0;
        for (int w = 0; w < WAVES_PER_BLOCK; ++w) acc += sred[w][threadIdx.x];
        partials[(size_t)blockIdx.x * 3 + threadIdx.x] = acc;
    }
}

__global__ void finalize_kernel(const double* __restrict__ partials, float* __restrict__ out_loss) {
    const int lane = threadIdx.x;  // 64 threads
    double b0 = 0.0, b1 = 0.0, b2 = 0.0;
    for (int i = lane; i < GRID_BLKS; i += 64) {
        b0 += partials[(size_t)i * 3 + 0];
        b1 += partials[(size_t)i * 3 + 1];
        b2 += partials[(size_t)i * 3 + 2];
    }
#pragma unroll
    for (int off = 32; off > 0; off >>= 1) {
        b0 += __shfl_xor(b0, off, 64);
        b1 += __shfl_xor(b1, off, 64);
        b2 += __shfl_xor(b2, off, 64);
    }
    if (lane == 0) {
        const double base = b0 / (double)BSZ;
        const double kge = b1 / ((double)BSZ * (double)MSZ);
        const double l2 = b2;
        out_loss[0] = (float)(base - KGE_W * kge + L2_W * l2);
    }
}

extern "C" void kernel_launch(void* const* d_in, const int* in_sizes, int n_in,
                              void* d_out, int out_size, void* d_ws, size_t ws_size,
                              hipStream_t stream) {
    const float* ent    = (const float*)d_in[0];
    const float* rel    = (const float*)d_in[1];
    const int*   items  = (const int*)d_in[2];
    const int*   labels = (const int*)d_in[3];
    const int*   mh     = (const int*)d_in[4];
    const int*   mr     = (const int*)d_in[5];
    const int*   mt     = (const int*)d_in[6];

    float* out = (float*)d_out;              // scores[16384] then loss at [16384]
    float* relsq = (float*)d_ws;             // 24 floats
    double* partials = (double*)((char*)d_ws + 256);  // GRID_BLKS*3 doubles

    relsumsq_kernel<<<NREL, 64, 0, stream>>>(rel, relsq);
    ripple_kernel<<<GRID_BLKS, 256, 0, stream>>>(ent, rel, items, labels, mh, mr, mt,
                                                 relsq, out, partials);
    finalize_kernel<<<1, 64, 0, stream>>>(partials, out + BSZ);
}